// Round 3
// baseline (303.761 us; speedup 1.0000x reference)
//
#include <hip/hip_runtime.h>
#include <math.h>

#define NNODES 8192
#define DIM 256
#define ALPHA 3.0f
#define SLOPE 0.2f
#define LOG2E 1.4426950408889634f

typedef float floatx4 __attribute__((ext_vector_type(4)));

// ---------------------------------------------------------------------------
// Kernel A: per-node scores s1[n] = tanh(a*emb1[idx[n]]) . w[:256]
//                           s2[n] = tanh(a*emb2[idx[n]]) . w[256:]
// One wave (64 lanes) per node; each lane handles 4 contiguous floats.
// (Round-1 lesson: NO single-address atomics — 8192 same-line device-scope
// atomicMax ops serialized for ~90 us across 8 XCDs.)
// ---------------------------------------------------------------------------
__global__ __launch_bounds__(256) void s_kernel(
    const int* __restrict__ idx,
    const float* __restrict__ e1, const float* __restrict__ e2,
    const float* __restrict__ w,
    float* __restrict__ s1, float* __restrict__ s2)
{
    const int waveId = threadIdx.x >> 6;
    const int lane   = threadIdx.x & 63;
    const int node   = (blockIdx.x << 2) + waveId;   // 4 waves/block
    const int row    = idx[node];

    const float4* e1v = (const float4*)(e1 + (size_t)row * DIM);
    const float4* e2v = (const float4*)(e2 + (size_t)row * DIM);
    const float4* w1v = (const float4*)w;
    const float4* w2v = (const float4*)(w + DIM);

    float4 a  = e1v[lane];
    float4 b  = e2v[lane];
    float4 w1 = w1v[lane];
    float4 w2 = w2v[lane];

    float acc1 = tanhf(ALPHA * a.x) * w1.x + tanhf(ALPHA * a.y) * w1.y
               + tanhf(ALPHA * a.z) * w1.z + tanhf(ALPHA * a.w) * w1.w;
    float acc2 = tanhf(ALPHA * b.x) * w2.x + tanhf(ALPHA * b.y) * w2.y
               + tanhf(ALPHA * b.z) * w2.z + tanhf(ALPHA * b.w) * w2.w;

    #pragma unroll
    for (int off = 32; off > 0; off >>= 1) {
        acc1 += __shfl_down(acc1, off);
        acc2 += __shfl_down(acc2, off);
    }
    if (lane == 0) {
        s1[node] = acc1;
        s2[node] = acc2;
    }
}

// ---------------------------------------------------------------------------
// Kernel B: WAVE-per-row, three cheap passes over L1-resident s2/idx,
// zero barriers, no prep kernel (round-2's single-block prep left the whole
// device idle for its duration + cost a kernel-boundary drain).
//
//   scores[i,j] = leaky_relu(s1[i] + s2[j] + b)   (lr(x) = max(x, 0.2x))
//   m_i = lr(s1[i] + b + max_j s2[j])             (exact: lr increasing)
//   out[i, idx[j]] = exp(scores - m_i) / sum_j exp(...)
//
// Pass 0: per-wave max of s2 (32 KB, L1) + per-wave "idx == arange" check.
// Pass 1: exp-sum -> butterfly shfl gives every lane the denominator.
// Pass 2: recompute exps (bit-identical sequence), stream float4 stores.
//
// ROUND-3 EXPERIMENT: stores are PLAIN (not nontemporal). Every prior
// version used __builtin_nontemporal_store for the 268 MB output stream;
// the harness fill that demonstrably sustains 6.4 TB/s uses plain stores
// through L2. NT demotion is the one shared untested feature of all
// previous ~292 us versions.
// ---------------------------------------------------------------------------
__global__ __launch_bounds__(256) void row_kernel(
    const float* __restrict__ s1, const float* __restrict__ s2,
    const int* __restrict__ idx, const float* __restrict__ att_b,
    float* __restrict__ out)
{
    const int lane = threadIdx.x & 63;
    const int wv   = threadIdx.x >> 6;
    const int row  = (blockIdx.x << 2) + wv;   // 4 rows per block

    const float4* s2v  = (const float4*)s2;
    const int4*   idxv = (const int4*)idx;

    // Pass 0: wave-local scan of s2 (max) and idx (identity check).
    float lmax = -3.402823466e38f;
    int ok = 1;
    #pragma unroll 4
    for (int k = 0; k < 32; ++k) {
        float4 v = s2v[k * 64 + lane];
        lmax = fmaxf(lmax, fmaxf(fmaxf(v.x, v.y), fmaxf(v.z, v.w)));
        int4 iv = idxv[k * 64 + lane];
        const int c0 = (k * 64 + lane) * 4;
        ok &= (iv.x == c0) & (iv.y == c0 + 1) & (iv.z == c0 + 2) & (iv.w == c0 + 3);
    }
    #pragma unroll
    for (int off = 32; off > 0; off >>= 1) {
        lmax = fmaxf(lmax, __shfl_xor(lmax, off));
        ok &= __shfl_xor(ok, off);
    }

    const float base = s1[row] + att_b[0];
    const float tm   = base + lmax;
    const float m    = fmaxf(tm, SLOPE * tm);    // exact row max of lr(scores)
    const float mexp = m * LOG2E;

    // Pass 1: softmax denominator.
    float dsum = 0.0f;
    #pragma unroll 4
    for (int k = 0; k < 32; ++k) {
        float4 v = s2v[k * 64 + lane];
        float x0 = base + v.x, x1 = base + v.y;
        float x2 = base + v.z, x3 = base + v.w;
        x0 = fmaxf(x0, SLOPE * x0);
        x1 = fmaxf(x1, SLOPE * x1);
        x2 = fmaxf(x2, SLOPE * x2);
        x3 = fmaxf(x3, SLOPE * x3);
        float e0 = __builtin_amdgcn_exp2f(fmaf(x0, LOG2E, -mexp));
        float e1 = __builtin_amdgcn_exp2f(fmaf(x1, LOG2E, -mexp));
        float e2 = __builtin_amdgcn_exp2f(fmaf(x2, LOG2E, -mexp));
        float e3 = __builtin_amdgcn_exp2f(fmaf(x3, LOG2E, -mexp));
        dsum += (e0 + e1) + (e2 + e3);
    }
    #pragma unroll
    for (int off = 32; off > 0; off >>= 1)
        dsum += __shfl_xor(dsum, off);           // all lanes hold full sum
    const float inv = 1.0f / dsum;

    float* orow = out + (size_t)row * NNODES;

    if (ok) {
        // Fast path: computed-address plain float4 stream (matches the
        // store pattern of the 6.4 TB/s fill kernel).
        #pragma unroll 4
        for (int k = 0; k < 32; ++k) {
            float4 v = s2v[k * 64 + lane];
            float x0 = base + v.x, x1 = base + v.y;
            float x2 = base + v.z, x3 = base + v.w;
            x0 = fmaxf(x0, SLOPE * x0);
            x1 = fmaxf(x1, SLOPE * x1);
            x2 = fmaxf(x2, SLOPE * x2);
            x3 = fmaxf(x3, SLOPE * x3);
            floatx4 o;
            o.x = __builtin_amdgcn_exp2f(fmaf(x0, LOG2E, -mexp)) * inv;
            o.y = __builtin_amdgcn_exp2f(fmaf(x1, LOG2E, -mexp)) * inv;
            o.z = __builtin_amdgcn_exp2f(fmaf(x2, LOG2E, -mexp)) * inv;
            o.w = __builtin_amdgcn_exp2f(fmaf(x3, LOG2E, -mexp)) * inv;
            *(floatx4*)(orow + (k * 64 + lane) * 4) = o;
        }
    } else {
        // General path: scatter via idx (L1/L2-resident).
        #pragma unroll 4
        for (int k = 0; k < 32; ++k) {
            float4 v = s2v[k * 64 + lane];
            int4  iv = idxv[k * 64 + lane];
            float x0 = base + v.x, x1 = base + v.y;
            float x2 = base + v.z, x3 = base + v.w;
            x0 = fmaxf(x0, SLOPE * x0);
            x1 = fmaxf(x1, SLOPE * x1);
            x2 = fmaxf(x2, SLOPE * x2);
            x3 = fmaxf(x3, SLOPE * x3);
            orow[iv.x] = __builtin_amdgcn_exp2f(fmaf(x0, LOG2E, -mexp)) * inv;
            orow[iv.y] = __builtin_amdgcn_exp2f(fmaf(x1, LOG2E, -mexp)) * inv;
            orow[iv.z] = __builtin_amdgcn_exp2f(fmaf(x2, LOG2E, -mexp)) * inv;
            orow[iv.w] = __builtin_amdgcn_exp2f(fmaf(x3, LOG2E, -mexp)) * inv;
        }
    }
}

extern "C" void kernel_launch(void* const* d_in, const int* in_sizes, int n_in,
                              void* d_out, int out_size, void* d_ws, size_t ws_size,
                              hipStream_t stream) {
    const int*   idx   = (const int*)d_in[0];
    const float* emb1  = (const float*)d_in[1];
    const float* emb2  = (const float*)d_in[2];
    const float* att_w = (const float*)d_in[3];
    const float* att_b = (const float*)d_in[4];
    float* out = (float*)d_out;

    float* s1 = (float*)d_ws;          // 8192 floats
    float* s2 = s1 + NNODES;           // 8192 floats

    s_kernel<<<NNODES / 4, 256, 0, stream>>>(idx, emb1, emb2, att_w, s1, s2);
    row_kernel<<<NNODES / 4, 256, 0, stream>>>(s1, s2, idx, att_b, out);
}